// Round 8
// baseline (59.116 us; speedup 1.0000x reference)
//
#include <hip/hip_runtime.h>
#include <math.h>

#define N 512
#define D 256
#define NPAIRS 261632.0f  // 512*511

typedef unsigned long long u64;
typedef unsigned int u32;

__constant__ float kRad2Deg = 57.29577951308232f; // 180/pi

__device__ __forceinline__ u64 shfl_xor_u64(u64 v, int m) {
    u32 lo = (u32)v, hi = (u32)(v >> 32);
    lo = (u32)__shfl_xor((int)lo, m, 64);
    hi = (u32)__shfl_xor((int)hi, m, 64);
    return ((u64)hi << 32) | (u64)lo;
}

// ---------------------------------------------------------------------------
// Kernel 1: per-row prep (verified R5-R7). Block = row i, 64 lanes.
// ---------------------------------------------------------------------------
__global__ __launch_bounds__(64) void prep_kernel(
        const float* __restrict__ f,
        const float* __restrict__ labels,
        float* __restrict__ rot,
        float* __restrict__ tvec,
        float* __restrict__ nrm,
        float* __restrict__ acc,
        unsigned* __restrict__ cnt) {
    const int i = blockIdx.x;
    const int l = threadIdx.x;

    const float4 v = ((const float4*)(f + i * D))[l];
    float ss = v.x * v.x + v.y * v.y + v.z * v.z + v.w * v.w;
#pragma unroll
    for (int off = 32; off > 0; off >>= 1) ss += __shfl_down(ss, off, 64);

    if (l == 0) {
        nrm[i] = ss;
        const float* p = labels + i * 9;
        float a1x = p[0], a1y = p[1], a1z = p[2];
        float a2x = p[3], a2y = p[4], a2z = p[5];
        float n1 = sqrtf(a1x * a1x + a1y * a1y + a1z * a1z);
        float b1x = a1x / n1, b1y = a1y / n1, b1z = a1z / n1;
        float dp = b1x * a2x + b1y * a2y + b1z * a2z;
        float cx = a2x - dp * b1x, cy = a2y - dp * b1y, cz = a2z - dp * b1z;
        float n2 = sqrtf(cx * cx + cy * cy + cz * cz);
        float b2x = cx / n2, b2y = cy / n2, b2z = cz / n2;
        float b3x = b1y * b2z - b1z * b2y;
        float b3y = b1z * b2x - b1x * b2z;
        float b3z = b1x * b2y - b1y * b2x;
        float det = b1x * (b2y * b3z - b2z * b3y)
                  - b1y * (b2x * b3z - b2z * b3x)
                  + b1z * (b2x * b3y - b2y * b3x);
        float inv = 1.0f / cbrtf(det);
        float* r = rot + i * 9;
        r[0] = b1x * inv; r[1] = b1y * inv; r[2] = b1z * inv;
        r[3] = b2x * inv; r[4] = b2y * inv; r[5] = b2z * inv;
        r[6] = b3x * inv; r[7] = b3y * inv; r[8] = b3z * inv;
        tvec[i * 3 + 0] = p[6];
        tvec[i * 3 + 1] = p[7];
        tvec[i * 3 + 2] = p[8];
        if (i == 0) { acc[0] = 0.0f; cnt[0] = 0u; }
    }
}

// ---------------------------------------------------------------------------
// Kernel 2: Gram matrix G = f * f^T (coalesced, LDS-tiled). Verified R7.
// ---------------------------------------------------------------------------
__global__ __launch_bounds__(256) void gram_kernel(
        const float* __restrict__ f,
        float* __restrict__ G) {
    __shared__ __attribute__((aligned(16))) float As[16][68];
    __shared__ __attribute__((aligned(16))) float Bs[16][68];
    const int tx = threadIdx.x & 15, ty = threadIdx.x >> 4;
    const int bi = (blockIdx.x >> 5) << 4;
    const int bj = (blockIdx.x & 31) << 4;

    float accv = 0.0f;
#pragma unroll
    for (int k0 = 0; k0 < D; k0 += 64) {
        const float4 av = *(const float4*)(f + (bi + ty) * D + k0 + tx * 4);
        const float4 bv = *(const float4*)(f + (bj + ty) * D + k0 + tx * 4);
        __syncthreads();
        *(float4*)&As[ty][tx * 4] = av;
        *(float4*)&Bs[ty][tx * 4] = bv;
        __syncthreads();
#pragma unroll
        for (int kk = 0; kk < 16; ++kk) {
            const float4 a = *(const float4*)&As[ty][kk * 4];
            const float4 b = *(const float4*)&Bs[tx][kk * 4];
            accv += a.x * b.x; accv += a.y * b.y;
            accv += a.z * b.z; accv += a.w * b.w;
        }
    }
    G[(bi + ty) * N + bj + tx] = accv;
}

// ---------------------------------------------------------------------------
// Kernel 3: per-wave row processing, ALL STATE IN NAMED REGISTERS (no arrays
// -> no scratch; R7's VGPR_Count=28 proved q[8] etc. spilled). Wave w of
// block b handles (row = 2b + (w>>1), criterion = w&1 ? SHIFT : THETA).
// Element e = r*64+lane lives in named regs q0..q7 (packed (key<<32)|E).
// 45-stage bitonic network emitted via macros with literal up-flags.
// ---------------------------------------------------------------------------

// compare-exchange with XOR-partner via lane shuffle; UP is compile-time or
// lane-uniform; keepmin = (UP == (lane has 0 in jj bit))
#define CE_SHFL(r, jj, UP) { \
    const u64 p_ = shfl_xor_u64(q##r, (jj)); \
    const bool km_ = ((UP) == ((lane & (jj)) == 0)); \
    q##r = ((q##r < p_) == km_) ? q##r : p_; }

#define SSTAGE(jj, U0,U1,U2,U3,U4,U5,U6,U7) \
    CE_SHFL(0,jj,U0) CE_SHFL(1,jj,U1) CE_SHFL(2,jj,U2) CE_SHFL(3,jj,U3) \
    CE_SHFL(4,jj,U4) CE_SHFL(5,jj,U5) CE_SHFL(6,jj,U6) CE_SHFL(7,jj,U7)

// in-thread cross-register compare-exchange
#define CE_REG(ra, rb, UP) { \
    const u64 a_ = q##ra, b_ = q##rb; \
    const bool altb_ = a_ < b_; \
    const u64 mn_ = altb_ ? a_ : b_, mx_ = altb_ ? b_ : a_; \
    q##ra = (UP) ? mn_ : mx_; \
    q##rb = (UP) ? mx_ : mn_; }

#define SUF1(r, off) { const float t_ = __shfl_down(s##r, (off), 64); \
    if (lane + (off) < 64) s##r += t_; }
#define SUF_STEP(off) SUF1(0,off) SUF1(1,off) SUF1(2,off) SUF1(3,off) \
                      SUF1(4,off) SUF1(5,off) SUF1(6,off) SUF1(7,off)

#define PROP1(r, off) { const float t_ = __shfl_up(h##r, (off), 64); \
    if (lane >= (off) && h##r < 0.0f) h##r = t_; }
#define PROP_STEP(off) PROP1(0,off) PROP1(1,off) PROP1(2,off) PROP1(3,off) \
                       PROP1(4,off) PROP1(5,off) PROP1(6,off) PROP1(7,off)

__global__ __launch_bounds__(256) void row_kernel(
        const float* __restrict__ G,
        const float* __restrict__ rot,
        const float* __restrict__ tvec,
        const float* __restrict__ nrm,
        float* __restrict__ acc,
        unsigned* __restrict__ cnt,
        float* __restrict__ out) {
    const int tid  = threadIdx.x;
    const int lane = tid & 63;
    const int wid  = tid >> 6;                  // 0..3
    const int i    = blockIdx.x * 2 + (wid >> 1);
    const bool isT = (wid & 1) == 0;

    float rotI[9];
#pragma unroll
    for (int c = 0; c < 9; ++c) rotI[c] = rot[i * 9 + c];
    const float tIx = tvec[i * 3 + 0];
    const float tIy = tvec[i * 3 + 1];
    const float tIz = tvec[i * 3 + 2];
    const float ni  = nrm[i];
    const float* __restrict__ Grow = G + i * N;

    // diagonal threshold (same op order as in-wave element -> bit-exact)
    float dthr;
    if (isT) {
        float trii = 0.0f;
#pragma unroll
        for (int c = 0; c < 9; ++c) trii += rotI[c] * rotI[c];
        const float ctv = fminf(1.0f, fmaxf(-1.0f, (trii - 1.0f) * 0.5f));
        dthr = acosf(ctv) * kRad2Deg;
    } else {
        dthr = 0.0f;
    }

    // ---- build packed elements (named regs) + lsum + direct diag denom ----
    u64 q0, q1, q2, q3, q4, q5, q6, q7;
    float lsum = 0.0f, dden = 0.0f;
#define BUILD(r) { \
    const int e = (r) * 64 + lane; \
    const float gij = Grow[e]; \
    const float d2  = ni + nrm[e] - 2.0f * gij; \
    float L, Ev; \
    if (e == i) { L = 0.0f; Ev = 0.0f; } \
    else { \
        const float dist = (d2 > 0.0f) ? sqrtf(d2) : 0.0f; \
        L  = -0.5f * dist; \
        Ev = expf(L); } \
    float keyv; \
    if (isT) { \
        const float* rp_ = rot + e * 9; \
        float tr8 = rotI[0]*rp_[0] + rotI[1]*rp_[1] + rotI[2]*rp_[2] \
                  + rotI[3]*rp_[3] + rotI[4]*rp_[4] + rotI[5]*rp_[5] \
                  + rotI[6]*rp_[6] + rotI[7]*rp_[7] + rotI[8]*rp_[8]; \
        const float ctv = fminf(1.0f, fmaxf(-1.0f, (tr8 - 1.0f) * 0.5f)); \
        keyv = acosf(ctv) * kRad2Deg; \
    } else { \
        const float dx = tIx - tvec[e * 3 + 0]; \
        const float dy = tIy - tvec[e * 3 + 1]; \
        const float dz = tIz - tvec[e * 3 + 2]; \
        const float sd2 = dx * dx + dy * dy + dz * dz; \
        keyv = ((sd2 > 0.0f) ? sqrtf(sd2) : 0.0f) * 100.0f; } \
    q##r  = ((u64)__float_as_uint(keyv) << 32) | (u64)__float_as_uint(Ev); \
    lsum += L; \
    dden += (keyv >= dthr) ? Ev : 0.0f; }
    BUILD(0) BUILD(1) BUILD(2) BUILD(3) BUILD(4) BUILD(5) BUILD(6) BUILD(7)
#undef BUILD
#pragma unroll
    for (int off = 32; off > 0; off >>= 1) {
        lsum += __shfl_down(lsum, off, 64);
        dden += __shfl_down(dden, off, 64);
    }

    // ---- bitonic sort ascending (key,E); e = r*64+lane; up = ((e&k)==0) ----
    { const bool U = ((lane &  2) == 0);                    // k=2
      SSTAGE(1, U,U,U,U,U,U,U,U) }
    { const bool U = ((lane &  4) == 0);                    // k=4
      SSTAGE(2, U,U,U,U,U,U,U,U) SSTAGE(1, U,U,U,U,U,U,U,U) }
    { const bool U = ((lane &  8) == 0);                    // k=8
      SSTAGE(4, U,U,U,U,U,U,U,U) SSTAGE(2, U,U,U,U,U,U,U,U)
      SSTAGE(1, U,U,U,U,U,U,U,U) }
    { const bool U = ((lane & 16) == 0);                    // k=16
      SSTAGE(8, U,U,U,U,U,U,U,U) SSTAGE(4, U,U,U,U,U,U,U,U)
      SSTAGE(2, U,U,U,U,U,U,U,U) SSTAGE(1, U,U,U,U,U,U,U,U) }
    { const bool U = ((lane & 32) == 0);                    // k=32
      SSTAGE(16, U,U,U,U,U,U,U,U) SSTAGE(8, U,U,U,U,U,U,U,U)
      SSTAGE(4, U,U,U,U,U,U,U,U)  SSTAGE(2, U,U,U,U,U,U,U,U)
      SSTAGE(1, U,U,U,U,U,U,U,U) }
    // k=64: up_r = ((r&1)==0)
    SSTAGE(32, true,false,true,false,true,false,true,false)
    SSTAGE(16, true,false,true,false,true,false,true,false)
    SSTAGE( 8, true,false,true,false,true,false,true,false)
    SSTAGE( 4, true,false,true,false,true,false,true,false)
    SSTAGE( 2, true,false,true,false,true,false,true,false)
    SSTAGE( 1, true,false,true,false,true,false,true,false)
    // k=128: up_r = ((r&2)==0)
    CE_REG(0,1,true) CE_REG(2,3,false) CE_REG(4,5,true) CE_REG(6,7,false)
    SSTAGE(32, true,true,false,false,true,true,false,false)
    SSTAGE(16, true,true,false,false,true,true,false,false)
    SSTAGE( 8, true,true,false,false,true,true,false,false)
    SSTAGE( 4, true,true,false,false,true,true,false,false)
    SSTAGE( 2, true,true,false,false,true,true,false,false)
    SSTAGE( 1, true,true,false,false,true,true,false,false)
    // k=256: up_r = ((r&4)==0)
    CE_REG(0,2,true) CE_REG(1,3,true) CE_REG(4,6,false) CE_REG(5,7,false)
    CE_REG(0,1,true) CE_REG(2,3,true) CE_REG(4,5,false) CE_REG(6,7,false)
    SSTAGE(32, true,true,true,true,false,false,false,false)
    SSTAGE(16, true,true,true,true,false,false,false,false)
    SSTAGE( 8, true,true,true,true,false,false,false,false)
    SSTAGE( 4, true,true,true,true,false,false,false,false)
    SSTAGE( 2, true,true,true,true,false,false,false,false)
    SSTAGE( 1, true,true,true,true,false,false,false,false)
    // k=512: up all true
    CE_REG(0,4,true) CE_REG(1,5,true) CE_REG(2,6,true) CE_REG(3,7,true)
    CE_REG(0,2,true) CE_REG(1,3,true) CE_REG(4,6,true) CE_REG(5,7,true)
    CE_REG(0,1,true) CE_REG(2,3,true) CE_REG(4,5,true) CE_REG(6,7,true)
    SSTAGE(32, true,true,true,true,true,true,true,true)
    SSTAGE(16, true,true,true,true,true,true,true,true)
    SSTAGE( 8, true,true,true,true,true,true,true,true)
    SSTAGE( 4, true,true,true,true,true,true,true,true)
    SSTAGE( 2, true,true,true,true,true,true,true,true)
    SSTAGE( 1, true,true,true,true,true,true,true,true)

    // ---- unpack into named key/suffix regs ----
    u32 k0 = (u32)(q0 >> 32), k1 = (u32)(q1 >> 32), k2 = (u32)(q2 >> 32),
        k3 = (u32)(q3 >> 32), k4 = (u32)(q4 >> 32), k5 = (u32)(q5 >> 32),
        k6 = (u32)(q6 >> 32), k7 = (u32)(q7 >> 32);
    float s0 = __uint_as_float((u32)q0), s1 = __uint_as_float((u32)q1),
          s2 = __uint_as_float((u32)q2), s3 = __uint_as_float((u32)q3),
          s4 = __uint_as_float((u32)q4), s5 = __uint_as_float((u32)q5),
          s6 = __uint_as_float((u32)q6), s7 = __uint_as_float((u32)q7);

    // ---- inclusive suffix-sum: in-lane (6 steps) then cross-reg carry ----
    SUF_STEP(1) SUF_STEP(2) SUF_STEP(4) SUF_STEP(8) SUF_STEP(16) SUF_STEP(32)
    {
        float c_ = 0.0f, tot_;
        tot_ = __shfl(s7, 0, 64); s7 += c_; c_ += tot_;
        tot_ = __shfl(s6, 0, 64); s6 += c_; c_ += tot_;
        tot_ = __shfl(s5, 0, 64); s5 += c_; c_ += tot_;
        tot_ = __shfl(s4, 0, 64); s4 += c_; c_ += tot_;
        tot_ = __shfl(s3, 0, 64); s3 += c_; c_ += tot_;
        tot_ = __shfl(s2, 0, 64); s2 += c_; c_ += tot_;
        tot_ = __shfl(s1, 0, 64); s1 += c_; c_ += tot_;
        tot_ = __shfl(s0, 0, 64); s0 += c_;
    }

    // ---- tie-run heads: h = head ? suffix : -1 ----
    float h0, h1, h2, h3, h4, h5, h6, h7;
    {
        u32 kp_;
        kp_ = (u32)__shfl_up((int)k0, 1, 64);
        h0 = ((lane == 0) || (k0 != kp_)) ? s0 : -1.0f;
#define HEADR(r, rprev) { \
        kp_ = (u32)__shfl_up((int)k##r, 1, 64); \
        const u32 cb_ = (u32)__shfl((int)k##rprev, 63, 64); \
        if (lane == 0) kp_ = cb_; \
        h##r = (k##r != kp_) ? s##r : -1.0f; }
        HEADR(1,0) HEADR(2,1) HEADR(3,2) HEADR(4,3)
        HEADR(5,4) HEADR(6,5) HEADR(7,6)
#undef HEADR
    }
    // in-lane "nearest valid below" fill (6 steps), then cross-reg fill
    PROP_STEP(1) PROP_STEP(2) PROP_STEP(4) PROP_STEP(8) PROP_STEP(16) PROP_STEP(32)
    {
        float cp_;
        cp_ = __shfl(h0, 63, 64); if (h1 < 0.0f) h1 = cp_;
        cp_ = __shfl(h1, 63, 64); if (h2 < 0.0f) h2 = cp_;
        cp_ = __shfl(h2, 63, 64); if (h3 < 0.0f) h3 = cp_;
        cp_ = __shfl(h3, 63, 64); if (h4 < 0.0f) h4 = cp_;
        cp_ = __shfl(h4, 63, 64); if (h5 < 0.0f) h5 = cp_;
        cp_ = __shfl(h5, 63, 64); if (h6 < 0.0f) h6 = cp_;
        cp_ = __shfl(h6, 63, 64); if (h7 < 0.0f) h7 = cp_;
    }

    // ---- sum of per-position log terms ----
    float tsum = logf(h0) + logf(h1) + logf(h2) + logf(h3)
               + logf(h4) + logf(h5) + logf(h6) + logf(h7);
#pragma unroll
    for (int off = 32; off > 0; off >>= 1) tsum += __shfl_down(tsum, off, 64);

    // ---- contribution + last-wave finalize ----
    if (lane == 0) {
        // tsum includes the diagonal position's term == log(dden); cancel it.
        float contrib = -0.5f * tsum + 0.5f * logf(dden);
        if (isT) contrib += lsum;
        atomicAdd(acc, contrib);
        __threadfence();
        const unsigned old = atomicAdd(cnt, 1u);
        if (old == (unsigned)(gridDim.x * 4 - 1)) {
            const float total = atomicAdd(acc, 0.0f);
            out[0] = -total / NPAIRS;
        }
    }
}

extern "C" void kernel_launch(void* const* d_in, const int* in_sizes, int n_in,
                              void* d_out, int out_size, void* d_ws, size_t ws_size,
                              hipStream_t stream) {
    const float* f      = (const float*)d_in[0];  // (512, 256) fp32
    const float* labels = (const float*)d_in[1];  // (512, 9)   fp32
    float* out = (float*)d_out;                   // scalar fp32
    float* ws  = (float*)d_ws;

    float*    rot  = ws;                    // 512*9
    float*    tvec = rot + N * 9;           // 512*3
    float*    nrm  = tvec + N * 3;          // 512
    float*    acc  = nrm + N;               // 1
    unsigned* cnt  = (unsigned*)(acc + 1);  // 1
    float*    G    = acc + 16;              // 512*512 (1 MB)

    prep_kernel<<<N, 64, 0, stream>>>(f, labels, rot, tvec, nrm, acc, cnt);
    gram_kernel<<<(N / 16) * (N / 16), 256, 0, stream>>>(f, G);
    row_kernel<<<N / 2, 256, 0, stream>>>(G, rot, tvec, nrm, acc, cnt, out);
}